// Round 16
// baseline (136.226 us; speedup 1.0000x reference)
//
#include <hip/hip_runtime.h>
#include <hip/hip_bf16.h>
#include <math.h>

// MultiHeadAttention: B=2, S=2048, D=1024, H=16, HD=64
// Pipeline: fused cvt (+mask preprocess) | QKV GEMM (MFMA bf16) | flash attn.
// Attn: ZERO synchronization. 2048 blocks of ONE wave (64 thr); each wave owns
// 32 q-rows (2 subtiles) and sweeps all 32 kv tiles. K *and* V are read
// directly from global in MFMA fragment order (written that way by the GEMM
// epilogue): every load is a coalesced 16B/lane dwordx4, L2-resident via XCD
// swizzle (4 heads/XCD). No LDS, no barriers, no staging -> waves de-phase
// freely and the compiler can pipeline loads across tile iterations.
// Swapped-QK (P^T in registers), fixed-shift exp2 softmax, shfl-only epilogue.
// r12-r15 lesson: ~80us plateau was barrier-lockstep structure, not occupancy.

typedef __bf16 bf16_t;
typedef __attribute__((ext_vector_type(8))) __bf16 bf16x8;
typedef __attribute__((ext_vector_type(4))) __bf16 bf16x4;
typedef __attribute__((ext_vector_type(4))) float f32x4;

#define B_  2
#define S_  2048
#define D_  1024
#define H_  16
#define HD_ 64
#define M_  (B_ * S_)   // 4096
#define K_  D_          // 1024
#define NT_ (S_ / 64)   // 32 kv tiles
#define LOG2E 1.44269504f

__device__ __forceinline__ f32x4 mfma16x16x32(bf16x8 a, bf16x8 b, f32x4 c) {
    return __builtin_amdgcn_mfma_f32_16x16x32_bf16(a, b, c, 0, 0, 0);
}

__device__ __forceinline__ void gload_lds16(const bf16_t* g, bf16_t* l) {
    __builtin_amdgcn_global_load_lds(
        (const __attribute__((address_space(1))) void*)g,
        (__attribute__((address_space(3))) void*)l,
        16, 0, 0);
}

// ---------------------------------------------------------------- conversion
// Segments: X (1,048,576 f4) | Wq | Wk | Wv (262,144 f4 each) | mask (1024 f4).
// Mask is pre-folded into exp2 domain: mk2 = mask*log2e - 8.
__global__ void cvt_all(const float* __restrict__ hs, const float* __restrict__ wq,
                        const float* __restrict__ wk, const float* __restrict__ wv,
                        const float* __restrict__ mask,
                        bf16_t* __restrict__ Xb, bf16_t* __restrict__ Wb3,
                        float* __restrict__ mk2) {
    const int i = blockIdx.x * blockDim.x + threadIdx.x;
    if (i >= 1835008) {                     // mask segment (block-aligned tail)
        const int off = i - 1835008;
        if (off < 1024) {
            float4 v = ((const float4*)mask)[off];
            v.x = v.x * LOG2E - 8.0f; v.y = v.y * LOG2E - 8.0f;
            v.z = v.z * LOG2E - 8.0f; v.w = v.w * LOG2E - 8.0f;
            ((float4*)mk2)[off] = v;
        }
        return;
    }
    const float* src; bf16_t* dst; int off;
    if (i < 1048576)      { src = hs; dst = Xb;            off = i; }
    else if (i < 1310720) { src = wq; dst = Wb3;           off = i - 1048576; }
    else if (i < 1572864) { src = wk; dst = Wb3 + 1048576; off = i - 1310720; }
    else                  { src = wv; dst = Wb3 + 2097152; off = i - 1572864; }
    float4 v = ((const float4*)src)[off];
    bf16x4 o;
    o[0] = (bf16_t)v.x; o[1] = (bf16_t)v.y;
    o[2] = (bf16_t)v.z; o[3] = (bf16_t)v.w;
    ((bf16x4*)dst)[off] = o;
}

// ---------------------------------------------------------------- QKV GEMM
// z=0 -> Q [B][H][S][HD]
// z=1 -> K in MFMA-A-fragment order:
//        Kf[bh][t][nb][hb][lane=kg*16+lq][e] = K[t*64+nb*16+lq][hb*32+kg*8+e]
// z=2 -> V in MFMA-B-fragment order:
//        Vf[bh][t][db][lane=kg*16+lq][e=nb*4+j] = V[t*64+nb*16+kg*4+j][db*16+lq]
__global__ __launch_bounds__(256, 2)
void gemm_qkv(const bf16_t* __restrict__ Xb, const bf16_t* __restrict__ Wb3,
              const float* __restrict__ bq, const float* __restrict__ bk,
              const float* __restrict__ bv,
              bf16_t* __restrict__ Qo, bf16_t* __restrict__ Kf,
              bf16_t* __restrict__ Vf) {
    __shared__ bf16_t smem[8192];           // A tile 128x32 | B tile 128x32 (16 KB)
    const int z = blockIdx.z;
    const bf16_t* Wb = Wb3 + (size_t)z * (D_ * K_);
    const float* bias = (z == 0) ? bq : (z == 1) ? bk : bv;

    const int tid  = threadIdx.x;
    const int lane = tid & 63;
    const int w    = tid >> 6;
    const int wr   = w >> 1, wc = w & 1;
    const int m0   = blockIdx.y * 128;
    const int n0   = blockIdx.x * 128;

    f32x4 acc[4][4];
    const f32x4 fzero = {0.f, 0.f, 0.f, 0.f};
#pragma unroll
    for (int i = 0; i < 4; i++)
#pragma unroll
        for (int j = 0; j < 4; j++) acc[i][j] = fzero;

    const int koff = (lane >> 4) * 8;

    for (int k0 = 0; k0 < K_; k0 += 32) {
#pragma unroll
        for (int i = 0; i < 4; i++) {
            const int chunk  = w * 4 + i;
            const int byteoff = chunk * 1024 + lane * 16;
            bf16_t* ldst = &smem[chunk * 512];          // wave-uniform base
            const bf16_t* gsrc;
            if (byteoff < 8192) {                        // A region
                int row = byteoff >> 6;
                int col = (byteoff & 63) >> 1;
                gsrc = Xb + (size_t)(m0 + row) * K_ + k0 + col;
            } else {                                     // B region
                int bo  = byteoff - 8192;
                int row = bo >> 6;
                int col = (bo & 63) >> 1;
                gsrc = Wb + (size_t)(n0 + row) * K_ + k0 + col;
            }
            gload_lds16(gsrc, ldst);
        }
        __syncthreads();

        bf16x8 af[4], bfr[4];
#pragma unroll
        for (int m = 0; m < 4; m++) {
            int row = wr * 64 + m * 16 + (lane & 15);
            af[m] = *(const bf16x8*)&smem[row * 32 + koff];
        }
#pragma unroll
        for (int n = 0; n < 4; n++) {
            int row = wc * 64 + n * 16 + (lane & 15);
            bfr[n] = *(const bf16x8*)&smem[4096 + row * 32 + koff];
        }
#pragma unroll
        for (int m = 0; m < 4; m++)
#pragma unroll
            for (int n = 0; n < 4; n++)
                acc[m][n] = mfma16x16x32(af[m], bfr[n], acc[m][n]);
        __syncthreads();
    }

#pragma unroll
    for (int m = 0; m < 4; m++) {
        const int gm    = m0 + wr * 64 + m * 16 + ((lane >> 4) << 2);
        const int bidx  = gm >> 11;
        const int sbase = gm & 2047;                    // multiple of 4
#pragma unroll
        for (int n = 0; n < 4; n++) {
            const int gn = n0 + wc * 64 + n * 16 + (lane & 15);
            const int h  = gn >> 6, hd = gn & 63;
            const float bias_v = bias[gn];
            const size_t bh = (size_t)bidx * H_ + h;
            if (z == 2) {
                // B-fragment V write: 4 contiguous e-slots = one 8B store
                const int t   = sbase >> 6, k0i = sbase & 63;
                const int nb  = k0i >> 4, kgf = (k0i >> 2) & 3;
                const int db  = hd >> 4,  lqf = hd & 15;
                bf16x4 pack;
#pragma unroll
                for (int j = 0; j < 4; j++)
                    pack[j] = (bf16_t)(acc[m][n][j] + bias_v);
                bf16_t* dst = Vf + ((bh * 32 + t) * 4 + db) * 1024 +
                    (kgf * 16 + lqf) * 16 + nb * 4;
                *(bf16x4*)dst = pack;
            } else if (z == 1) {
                // A-fragment K write: j walks lanes (stride 8 elems), e fixed
                const int t   = sbase >> 6;
                const int nb  = (sbase >> 4) & 3, lqb = sbase & 15;
                const int hb  = hd >> 5, kgf = (hd >> 3) & 3, e = hd & 7;
                bf16_t* base = Kf + (((bh * 32 + t) * 4 + nb) * 2 + hb) * 512 +
                    kgf * 128 + e;
#pragma unroll
                for (int j = 0; j < 4; j++)
                    base[(lqb + j) * 8] = (bf16_t)(acc[m][n][j] + bias_v);
            } else {
#pragma unroll
                for (int j = 0; j < 4; j++) {
                    float y = acc[m][n][j] + bias_v;
                    Qo[(bh * S_ + sbase + j) * HD_ + hd] = (bf16_t)y;
                }
            }
        }
    }
}

// ---------------------------------------------------------------- attention
// 2048 one-wave blocks. flat = xcd(3b) | {head-in-xcd(2b) | qw(6b)}.
// Wave owns q rows [qw*32, qw*32+32), sweeps all 32 kv tiles. No LDS, no sync.
__global__ __launch_bounds__(64, 2)
void attn_fwd(const bf16_t* __restrict__ Qb, const bf16_t* __restrict__ Kf,
              const bf16_t* __restrict__ Vf, const float* __restrict__ mk2b,
              float* __restrict__ out) {
    const int flat = blockIdx.x;
    const int xcd  = flat & 7;
    const int idx  = flat >> 3;            // 0..255
    const int bh   = xcd * 4 + (idx >> 6); // 0..31
    const int qw   = idx & 63;             // 64 wave-units per head
    const int b    = bh >> 4;
    const int h    = bh & 15;

    const int lane = threadIdx.x & 63;
    const int lq   = lane & 15;
    const int kg   = lane >> 4;            // 0..3
    const int koff = kg * 8;

    const bf16_t* Qh = Qb + (size_t)bh * S_ * HD_;
    const bf16_t* Kh = Kf + (size_t)bh * 32 * 4096;   // [t][nb][hb][lane][8]
    const bf16_t* Vh = Vf + (size_t)bh * 32 * 4096;   // [t][db][lane][16]
    const float*  mk = mk2b + (size_t)b * S_;         // pre-folded mask

    // ---- Q fragments: 2 subtiles of 16 rows (32 rows/wave)
    const int qbase = qw * 32;
    bf16x8 qf0[2], qf1[2];
#pragma unroll
    for (int s = 0; s < 2; s++) {
        const bf16_t* qr = Qh + (size_t)(qbase + s * 16 + lq) * HD_;
        qf0[s] = *(const bf16x8*)(qr + koff);
        qf1[s] = *(const bf16x8*)(qr + 32 + koff);
    }

    const f32x4 fzero = {0.f, 0.f, 0.f, 0.f};
    f32x4 of[2][4];
    float lsum[2] = {0.f, 0.f};
#pragma unroll
    for (int s = 0; s < 2; s++)
#pragma unroll
        for (int i = 0; i < 4; i++) of[s][i] = fzero;

    const float cs = 0.125f * LOG2E;       // fold 1/sqrt(64) and log2e

    for (int t = 0; t < NT_; ++t) {
        const int kv0 = t * 64;
        const bf16_t* Kt = Kh + (size_t)t * 4096;
        const bf16_t* Vt = Vh + (size_t)t * 4096;

        // ---- K fragments: coalesced 16B/lane from frag-order global
        bf16x8 kf0[4], kf1[4];
#pragma unroll
        for (int nb = 0; nb < 4; nb++) {
            kf0[nb] = *(const bf16x8*)(Kt + (nb * 2 + 0) * 512 + lane * 8);
            kf1[nb] = *(const bf16x8*)(Kt + (nb * 2 + 1) * 512 + lane * 8);
        }
        // ---- V fragments: coalesced, q-independent (shared by subtiles)
        bf16x8 va[4], vb[4];
#pragma unroll
        for (int db = 0; db < 4; db++) {
            const bf16_t* vp = Vt + db * 1024 + lane * 16;
            va[db] = *(const bf16x8*)(vp);
            vb[db] = *(const bf16x8*)(vp + 8);
        }
        // ---- mask values (pre-folded): k = kv0 + nb*16 + kg*4 + j
        f32x4 mvf[4];
#pragma unroll
        for (int nb = 0; nb < 4; nb++)
            mvf[nb] = *(const f32x4*)&mk[kv0 + nb * 16 + kg * 4];

#pragma unroll
        for (int s = 0; s < 2; s++) {
            // ---- scores transposed: sc[nb] = mfma(K, Q) -> D[k=kg*4+j][q=lq]
            f32x4 sc[4];
#pragma unroll
            for (int nb = 0; nb < 4; nb++) {
                f32x4 tacc = fzero;
                tacc = mfma16x16x32(kf0[nb], qf0[s], tacc);
                tacc = mfma16x16x32(kf1[nb], qf1[s], tacc);
                sc[nb] = tacc;
            }

            // ---- P^T = exp2(sc*cs + mk2) in-lane; permuted-k A fragments
            bf16x8 pa0, pa1;
#pragma unroll
            for (int nb = 0; nb < 4; nb++)
#pragma unroll
                for (int j = 0; j < 4; j++) {
                    float p = exp2f(sc[nb][j] * cs + mvf[nb][j]);
                    lsum[s] += p;
                    const int e = (nb & 1) * 4 + j;
                    if (nb < 2) pa0[e] = (bf16_t)p; else pa1[e] = (bf16_t)p;
                }

            // ---- O += P V (permuted-k consistent: va/vb e-order = nb*4+j)
#pragma unroll
            for (int db = 0; db < 4; db++) {
                of[s][db] = mfma16x16x32(pa0, va[db], of[s][db]);
                of[s][db] = mfma16x16x32(pa1, vb[db], of[s][db]);
            }
        }
    }

    // ---- finalize: lane's lsum covers its (kg,nb,j) k-subset at q=lq.
    // Reduce across kg groups, then gather l(q=kg*4+j) via shfl (no LDS).
#pragma unroll
    for (int s = 0; s < 2; s++) {
        float l = lsum[s];
        l += __shfl_xor(l, 16, 64);
        l += __shfl_xor(l, 32, 64);
        float inv[4];
#pragma unroll
        for (int j = 0; j < 4; j++)
            inv[j] = 1.0f / __shfl(l, kg * 4 + j, 16);
#pragma unroll
        for (int db = 0; db < 4; db++) {
            const int d = h * HD_ + db * 16 + lq;
#pragma unroll
            for (int j = 0; j < 4; j++) {
                const int row = qbase + s * 16 + kg * 4 + j;
                out[((size_t)b * S_ + row) * D_ + d] = of[s][db][j] * inv[j];
            }
        }
    }
}

// ---------------------------------------------------------------- launch
extern "C" void kernel_launch(void* const* d_in, const int* in_sizes, int n_in,
                              void* d_out, int out_size, void* d_ws, size_t ws_size,
                              hipStream_t stream) {
    const float* hs   = (const float*)d_in[0];
    const float* mask = (const float*)d_in[1];
    const float* Wq   = (const float*)d_in[2];
    const float* bq   = (const float*)d_in[3];
    const float* Wk   = (const float*)d_in[4];
    const float* bk   = (const float*)d_in[5];
    const float* Wv   = (const float*)d_in[6];
    const float* bv   = (const float*)d_in[7];
    float* out = (float*)d_out;

    char* ws = (char*)d_ws;
    bf16_t* Xb  = (bf16_t*)(ws);                    //  8,388,608 B  [4096][1024]
    bf16_t* Wb3 = (bf16_t*)(ws + 8388608);          //  6,291,456 B  3x[1024][1024]
    bf16_t* Qb  = (bf16_t*)(ws + 14680064);         //  8,388,608 B  [B][H][S][HD]
    bf16_t* Kfr = (bf16_t*)(ws + 23068672);         //  8,388,608 B  A-frag order
    bf16_t* Vfr = (bf16_t*)(ws + 31457280);         //  8,388,608 B  B-frag order
    float*  mk2 = (float*)(ws + 39845888);          //     16,384 B  folded mask

    cvt_all<<<7172, 256, 0, stream>>>(hs, Wq, Wk, Wv, mask, Xb, Wb3, mk2);

    dim3 ggrid(D_ / 128, M_ / 128, 3);              // (8, 32, 3)
    gemm_qkv<<<ggrid, 256, 0, stream>>>(Xb, Wb3, bq, bk, bv, Qb, Kfr, Vfr);

    attn_fwd<<<2048, 64, 0, stream>>>(Qb, Kfr, Vfr, mk2, out);
}

// Round 17
// 101.919 us; speedup vs baseline: 1.3366x; 1.3366x over previous
//
#include <hip/hip_runtime.h>
#include <hip/hip_bf16.h>
#include <math.h>

// MultiHeadAttention: B=2, S=2048, D=1024, H=16, HD=64
// Pipeline: fused cvt (+mask prefold) | QKV GEMM (MFMA bf16) | flash attn.
// Attn (r14 base): 512 blocks (128-row Q tiles), 4 waves x 32 rows (2 subtiles
// sharing K frags, V frags, mask). Swapped-QK: P^T in registers, never LDS.
// K staged via global_load_lds (2-phase dbuf, one __syncthreads/iter; LDS 16K).
// V direct from global in MFMA-B-fragment order (coalesced, L2-resident).
// r17 arithmetic eliminations:
//  - mask rides the QK MFMA accumulator (C-in = prefolded mask) -> no FMA pass
//  - Q pre-scaled by 0.125*log2e at GEMM epilogue -> P = exp2(sc) directly
//  - denominator via ones-column MFMA -> no lsum VALU, no epilogue shuffles
// r12-r16 lesson: occupancy/sync scans (2-16 waves/CU, sync none->full) all
// land 80-95us; the lever left is per-tile instruction count.

typedef __bf16 bf16_t;
typedef __attribute__((ext_vector_type(8))) __bf16 bf16x8;
typedef __attribute__((ext_vector_type(4))) __bf16 bf16x4;
typedef __attribute__((ext_vector_type(4))) float f32x4;

#define B_  2
#define S_  2048
#define D_  1024
#define H_  16
#define HD_ 64
#define M_  (B_ * S_)   // 4096
#define K_  D_          // 1024
#define NT_ (S_ / 64)   // 32 kv tiles
#define LOG2E 1.44269504f
#define CS_Q (0.125f * LOG2E)   // folded into Q at GEMM epilogue

__device__ __forceinline__ f32x4 mfma16x16x32(bf16x8 a, bf16x8 b, f32x4 c) {
    return __builtin_amdgcn_mfma_f32_16x16x32_bf16(a, b, c, 0, 0, 0);
}

__device__ __forceinline__ void gload_lds16(const bf16_t* g, bf16_t* l) {
    __builtin_amdgcn_global_load_lds(
        (const __attribute__((address_space(1))) void*)g,
        (__attribute__((address_space(3))) void*)l,
        16, 0, 0);
}

// ---------------------------------------------------------------- conversion
// Segments: X (1,048,576 f4) | Wq | Wk | Wv (262,144 f4 each) | mask (1024 f4).
// Mask pre-folded into exp2 domain: mk2 = mask*log2e - 8.
__global__ void cvt_all(const float* __restrict__ hs, const float* __restrict__ wq,
                        const float* __restrict__ wk, const float* __restrict__ wv,
                        const float* __restrict__ mask,
                        bf16_t* __restrict__ Xb, bf16_t* __restrict__ Wb3,
                        float* __restrict__ mk2) {
    const int i = blockIdx.x * blockDim.x + threadIdx.x;
    if (i >= 1835008) {                     // mask segment (block-aligned tail)
        const int off = i - 1835008;
        if (off < 1024) {
            float4 v = ((const float4*)mask)[off];
            v.x = v.x * LOG2E - 8.0f; v.y = v.y * LOG2E - 8.0f;
            v.z = v.z * LOG2E - 8.0f; v.w = v.w * LOG2E - 8.0f;
            ((float4*)mk2)[off] = v;
        }
        return;
    }
    const float* src; bf16_t* dst; int off;
    if (i < 1048576)      { src = hs; dst = Xb;            off = i; }
    else if (i < 1310720) { src = wq; dst = Wb3;           off = i - 1048576; }
    else if (i < 1572864) { src = wk; dst = Wb3 + 1048576; off = i - 1310720; }
    else                  { src = wv; dst = Wb3 + 2097152; off = i - 1572864; }
    float4 v = ((const float4*)src)[off];
    bf16x4 o;
    o[0] = (bf16_t)v.x; o[1] = (bf16_t)v.y;
    o[2] = (bf16_t)v.z; o[3] = (bf16_t)v.w;
    ((bf16x4*)dst)[off] = o;
}

// ---------------------------------------------------------------- QKV GEMM
// z=0 -> Q [B][H][S][HD], PRE-SCALED by CS_Q (0.125*log2e)
// z=1 -> K [B][H][S][HD]
// z=2 -> V in MFMA-B-fragment order: Vfrag[bh][t][db][lane=kg*16+lq][e=nb*4+j]
//        holding V[k = t*64 + nb*16 + kg*4 + j][d = db*16 + lq].
__global__ __launch_bounds__(256, 2)
void gemm_qkv(const bf16_t* __restrict__ Xb, const bf16_t* __restrict__ Wb3,
              const float* __restrict__ bq, const float* __restrict__ bk,
              const float* __restrict__ bv,
              bf16_t* __restrict__ Qo, bf16_t* __restrict__ Ko,
              bf16_t* __restrict__ Vf) {
    __shared__ bf16_t smem[8192];           // A tile 128x32 | B tile 128x32 (16 KB)
    const int z = blockIdx.z;
    const bf16_t* Wb = Wb3 + (size_t)z * (D_ * K_);
    const float* bias = (z == 0) ? bq : (z == 1) ? bk : bv;

    const int tid  = threadIdx.x;
    const int lane = tid & 63;
    const int w    = tid >> 6;
    const int wr   = w >> 1, wc = w & 1;
    const int m0   = blockIdx.y * 128;
    const int n0   = blockIdx.x * 128;

    f32x4 acc[4][4];
    const f32x4 fzero = {0.f, 0.f, 0.f, 0.f};
#pragma unroll
    for (int i = 0; i < 4; i++)
#pragma unroll
        for (int j = 0; j < 4; j++) acc[i][j] = fzero;

    const int koff = (lane >> 4) * 8;

    for (int k0 = 0; k0 < K_; k0 += 32) {
#pragma unroll
        for (int i = 0; i < 4; i++) {
            const int chunk  = w * 4 + i;
            const int byteoff = chunk * 1024 + lane * 16;
            bf16_t* ldst = &smem[chunk * 512];          // wave-uniform base
            const bf16_t* gsrc;
            if (byteoff < 8192) {                        // A region
                int row = byteoff >> 6;
                int col = (byteoff & 63) >> 1;
                gsrc = Xb + (size_t)(m0 + row) * K_ + k0 + col;
            } else {                                     // B region
                int bo  = byteoff - 8192;
                int row = bo >> 6;
                int col = (bo & 63) >> 1;
                gsrc = Wb + (size_t)(n0 + row) * K_ + k0 + col;
            }
            gload_lds16(gsrc, ldst);
        }
        __syncthreads();

        bf16x8 af[4], bfr[4];
#pragma unroll
        for (int m = 0; m < 4; m++) {
            int row = wr * 64 + m * 16 + (lane & 15);
            af[m] = *(const bf16x8*)&smem[row * 32 + koff];
        }
#pragma unroll
        for (int n = 0; n < 4; n++) {
            int row = wc * 64 + n * 16 + (lane & 15);
            bfr[n] = *(const bf16x8*)&smem[4096 + row * 32 + koff];
        }
#pragma unroll
        for (int m = 0; m < 4; m++)
#pragma unroll
            for (int n = 0; n < 4; n++)
                acc[m][n] = mfma16x16x32(af[m], bfr[n], acc[m][n]);
        __syncthreads();
    }

#pragma unroll
    for (int m = 0; m < 4; m++) {
        const int gm    = m0 + wr * 64 + m * 16 + ((lane >> 4) << 2);
        const int bidx  = gm >> 11;
        const int sbase = gm & 2047;                    // multiple of 4
#pragma unroll
        for (int n = 0; n < 4; n++) {
            const int gn = n0 + wc * 64 + n * 16 + (lane & 15);
            const int h  = gn >> 6, hd = gn & 63;
            const float bias_v = bias[gn];
            const size_t bh = (size_t)bidx * H_ + h;
            if (z == 2) {
                // fragment-order V write: 4 contiguous e-slots = one 8B store
                const int t   = sbase >> 6, k0i = sbase & 63;
                const int nb  = k0i >> 4, kgf = (k0i >> 2) & 3;
                const int db  = hd >> 4,  lqf = hd & 15;
                bf16x4 pack;
#pragma unroll
                for (int j = 0; j < 4; j++)
                    pack[j] = (bf16_t)(acc[m][n][j] + bias_v);
                bf16_t* dst = Vf + ((bh * 32 + t) * 4 + db) * 1024 +
                    (kgf * 16 + lqf) * 16 + nb * 4;
                *(bf16x4*)dst = pack;
            } else if (z == 0) {
#pragma unroll
                for (int j = 0; j < 4; j++) {
                    float y = (acc[m][n][j] + bias_v) * CS_Q;
                    Qo[(bh * S_ + sbase + j) * HD_ + hd] = (bf16_t)y;
                }
            } else {
#pragma unroll
                for (int j = 0; j < 4; j++) {
                    float y = acc[m][n][j] + bias_v;
                    Ko[(bh * S_ + sbase + j) * HD_ + hd] = (bf16_t)y;
                }
            }
        }
    }
}

// ---------------------------------------------------------------- attention
// 1-D grid of 512 (16 qtiles x 32 heads), XCD-aware: xcd = flat&7 owns 4 heads.
// LDS 16K: K dbuf 2x8K. V direct from global (frag order). No epilogue LDS.
__global__ __launch_bounds__(256, 2)
void attn_fwd(const bf16_t* __restrict__ Qb, const bf16_t* __restrict__ Kb,
              const bf16_t* __restrict__ Vf, const float* __restrict__ mk2b,
              float* __restrict__ out) {
    const int flat = blockIdx.x;
    const int xcd  = flat & 7;
    const int idx  = flat >> 3;            // 0..63
    const int bh   = xcd * 4 + (idx >> 4); // 0..31
    const int qt   = idx & 15;             // 0..15 (128-row tiles)
    const int b    = bh >> 4;
    const int h    = bh & 15;

    const int tid  = threadIdx.x, lane = tid & 63, w = tid >> 6;

    const bf16_t* Qh = Qb + (size_t)bh * S_ * HD_;
    const bf16_t* Kh = Kb + (size_t)bh * S_ * HD_;
    const bf16_t* Vh = Vf + (size_t)bh * 32 * 4096;   // [t][db][lane][16]
    const float*  mk = mk2b + (size_t)b * S_;         // pre-folded mask

    __shared__ char ShBuf[16384];          // 2 x K 8K

    const int lq   = lane & 15;
    const int kg   = lane >> 4;            // 0..3
    const int koff = kg * 8;
    const int rsub = lane >> 3;            // staging: row-in-chunk 0..7
    const int csl8 = (lane & 7) * 8;       // staging: 16B slot -> elements

    auto stageK = [&](int kv0, int buf) {
        bf16_t* base = (bf16_t*)(ShBuf + buf * 8192);
#pragma unroll
        for (int i = 0; i < 2; i++) {
            const int c = w * 2 + i;                    // 0..7, wave-uniform
            bf16_t* ldst = base + c * 512;              // 1 KB chunks
            const int cel = csl8 ^ (rsub * 8);          // pre-swizzled source col
            const bf16_t* gsrc = Kh + (size_t)(kv0 + c * 8 + rsub) * HD_ + cel;
            gload_lds16(gsrc, ldst);
        }
    };

    // ---- Q fragments: 2 subtiles of 16 rows (32 rows/wave, block tile 128)
    const int qbase = qt * 128 + w * 32;
    bf16x8 qf0[2], qf1[2];
#pragma unroll
    for (int s = 0; s < 2; s++) {
        const bf16_t* qr = Qh + (size_t)(qbase + s * 16 + lq) * HD_;
        qf0[s] = *(const bf16x8*)(qr + koff);
        qf1[s] = *(const bf16x8*)(qr + 32 + koff);
    }

    // ---- constant ones B-fragment (denominator column)
    bf16x8 ones;
#pragma unroll
    for (int e = 0; e < 8; e++) ones[e] = (bf16_t)1.0f;

    const f32x4 fzero = {0.f, 0.f, 0.f, 0.f};
    f32x4 of[2][4];
    f32x4 of_l[2];                          // denominator accumulators
#pragma unroll
    for (int s = 0; s < 2; s++) {
        of_l[s] = fzero;
#pragma unroll
        for (int i = 0; i < 4; i++) of[s][i] = fzero;
    }

    const int rdsw = (lq & 7) << 4;        // K read swizzle: (row&7)<<4 bytes

    stageK(0, 0);
    __syncthreads();

    for (int t = 0; t < NT_; ++t) {
        const int cur = t & 1;
        const int kv0 = t * 64;
        if (t + 1 < NT_) stageK((t + 1) * 64, cur ^ 1); // overlaps compute below

        // ---- V fragments direct from global (frag order, coalesced);
        //      q-independent -> shared by both subtiles. Issued early.
        const bf16_t* Vt_ = Vh + (size_t)t * 4096;
        bf16x8 va[4], vb[4];
#pragma unroll
        for (int db = 0; db < 4; db++) {
            const bf16_t* vp = Vt_ + db * 1024 + lane * 16;
            va[db] = *(const bf16x8*)(vp);
            vb[db] = *(const bf16x8*)(vp + 8);
        }

        // ---- mask (pre-folded) as MFMA C-in: C[row=k=kg*4+j] = mk2[k]
        f32x4 mC[4];
#pragma unroll
        for (int nb = 0; nb < 4; nb++)
            mC[nb] = *(const f32x4*)&mk[kv0 + nb * 16 + kg * 4];

        const char* KB = ShBuf + cur * 8192;

        // ---- K fragments (A-operand: K[k=nb*16+lq][hd=kg*8+e]), shared by s
        bf16x8 kf0[4], kf1[4];
#pragma unroll
        for (int nb = 0; nb < 4; nb++) {
            const char* kr = KB + (nb * 16 + lq) * 128;
            kf0[nb] = *(const bf16x8*)(kr + ((kg * 16) ^ rdsw));
            kf1[nb] = *(const bf16x8*)(kr + ((64 + kg * 16) ^ rdsw));
        }

#pragma unroll
        for (int s = 0; s < 2; s++) {
            // ---- scores transposed, mask pre-added via C-in:
            //      sc[nb] = K Q^T * (Q pre-scaled) + mk2  -> D[k=kg*4+j][q=lq]
            f32x4 sc[4];
#pragma unroll
            for (int nb = 0; nb < 4; nb++) {
                f32x4 tacc = mC[nb];
                tacc = mfma16x16x32(kf0[nb], qf0[s], tacc);
                tacc = mfma16x16x32(kf1[nb], qf1[s], tacc);
                sc[nb] = tacc;
            }

            // ---- P^T = exp2(sc) in-lane (no mul, no add); permuted-k A frags
            bf16x8 pa0, pa1;
#pragma unroll
            for (int nb = 0; nb < 4; nb++)
#pragma unroll
                for (int j = 0; j < 4; j++) {
                    float p = exp2f(sc[nb][j]);
                    const int e = (nb & 1) * 4 + j;
                    if (nb < 2) pa0[e] = (bf16_t)p; else pa1[e] = (bf16_t)p;
                }

            // ---- O += P V; denominator += P * 1 (ones-column MFMA)
#pragma unroll
            for (int db = 0; db < 4; db++) {
                of[s][db] = mfma16x16x32(pa0, va[db], of[s][db]);
                of[s][db] = mfma16x16x32(pa1, vb[db], of[s][db]);
            }
            of_l[s] = mfma16x16x32(pa0, ones, of_l[s]);
            of_l[s] = mfma16x16x32(pa1, ones, of_l[s]);
        }

        // one sync per iter: publishes stageK(t+1) (vmcnt drain) AND guards
        // K buffer reuse (stageK(t+2) overwrites buf[cur] next iteration).
        __syncthreads();
    }

    // ---- finalize: of_l[s][j] = sum_k P[k][q=kg*4+j], replicated over lq.
    // No shuffles, no LDS: divide and write.
#pragma unroll
    for (int s = 0; s < 2; s++) {
        float inv[4];
#pragma unroll
        for (int j = 0; j < 4; j++) inv[j] = 1.0f / of_l[s][j];
#pragma unroll
        for (int db = 0; db < 4; db++) {
            const int d = h * HD_ + db * 16 + lq;
#pragma unroll
            for (int j = 0; j < 4; j++) {
                const int row = qbase + s * 16 + kg * 4 + j;
                out[((size_t)b * S_ + row) * D_ + d] = of[s][db][j] * inv[j];
            }
        }
    }
}

// ---------------------------------------------------------------- launch
extern "C" void kernel_launch(void* const* d_in, const int* in_sizes, int n_in,
                              void* d_out, int out_size, void* d_ws, size_t ws_size,
                              hipStream_t stream) {
    const float* hs   = (const float*)d_in[0];
    const float* mask = (const float*)d_in[1];
    const float* Wq   = (const float*)d_in[2];
    const float* bq   = (const float*)d_in[3];
    const float* Wk   = (const float*)d_in[4];
    const float* bk   = (const float*)d_in[5];
    const float* Wv   = (const float*)d_in[6];
    const float* bv   = (const float*)d_in[7];
    float* out = (float*)d_out;

    char* ws = (char*)d_ws;
    bf16_t* Xb  = (bf16_t*)(ws);                    //  8,388,608 B  [4096][1024]
    bf16_t* Wb3 = (bf16_t*)(ws + 8388608);          //  6,291,456 B  3x[1024][1024]
    bf16_t* Qb  = (bf16_t*)(ws + 14680064);         //  8,388,608 B  [B][H][S][HD]
    bf16_t* Kb  = (bf16_t*)(ws + 23068672);         //  8,388,608 B  [B][H][S][HD]
    bf16_t* Vfr = (bf16_t*)(ws + 31457280);         //  8,388,608 B  B-frag order
    float*  mk2 = (float*)(ws + 39845888);          //     16,384 B  folded mask

    cvt_all<<<7172, 256, 0, stream>>>(hs, Wq, Wk, Wv, mask, Xb, Wb3, mk2);

    dim3 ggrid(D_ / 128, M_ / 128, 3);              // (8, 32, 3)
    gemm_qkv<<<ggrid, 256, 0, stream>>>(Xb, Wb3, bq, bk, bv, Qb, Kb, Vfr);

    attn_fwd<<<512, 256, 0, stream>>>(Qb, Kb, Vfr, mk2, out);
}